// Round 2
// baseline (321.038 us; speedup 1.0000x reference)
//
#include <hip/hip_runtime.h>
#include <hip/hip_bf16.h>

// Problem: B=2, T=2048, E=1024, H=16, D=64.
// Inputs are float32 (per reference dtypes); mask int32 [B,T,T]; output f32.
// Internally: bf16 MFMA pipeline (harness tolerance is 2% of max|ref|).

typedef __bf16 bf8_t  __attribute__((ext_vector_type(8)));
typedef float  f4_t   __attribute__((ext_vector_type(4)));

constexpr int Bb = 2, Tt = 2048, Hh = 16, Dd = 64;

// ------------------------------------------------------------ f32 -> bf16
// embed [4096*1024] f32 -> bf16. 4096 blocks x 256 threads x 4 elems.
__global__ __launch_bounds__(256) void convert_kernel(
    const float* __restrict__ in, __bf16* __restrict__ out)
{
    int i = (blockIdx.x * 256 + threadIdx.x) * 4;
    float4 v = *reinterpret_cast<const float4*>(in + i);
    __bf16 o[4] = {(__bf16)v.x, (__bf16)v.y, (__bf16)v.z, (__bf16)v.w};
    *reinterpret_cast<ulong1*>(out + i) = *reinterpret_cast<ulong1*>(o);
}

// ------------------------------------------------------------ transpose+cast
// W [1024 k][1024 n] f32 -> Wt [1024 n][1024 k] bf16, 4 matrices via blockIdx.z
__global__ __launch_bounds__(256) void transpose_kernel(
    const float* __restrict__ w0, const float* __restrict__ w1,
    const float* __restrict__ w2, const float* __restrict__ w3,
    __bf16* __restrict__ o0, __bf16* __restrict__ o1,
    __bf16* __restrict__ o2, __bf16* __restrict__ o3)
{
    const float* in; __bf16* out;
    switch (blockIdx.z) {
        case 0: in = w0; out = o0; break;
        case 1: in = w1; out = o1; break;
        case 2: in = w2; out = o2; break;
        default: in = w3; out = o3; break;
    }
    __shared__ float t[32][33];
    int x  = threadIdx.x & 31;
    int y0 = threadIdx.x >> 5;          // 0..7
    int bx = blockIdx.x * 32;           // n offset
    int by = blockIdx.y * 32;           // k offset
    #pragma unroll
    for (int i = 0; i < 4; i++) {
        int y = y0 + i * 8;
        t[y][x] = in[(size_t)(by + y) * 1024 + bx + x];
    }
    __syncthreads();
    #pragma unroll
    for (int i = 0; i < 4; i++) {
        int y = y0 + i * 8;
        out[(size_t)(bx + y) * 1024 + by + x] = (__bf16)t[x][y];
    }
}

// ---------------------------------------------------------------- GEMM body
// C[M=4096,N=1024] = A[4096,1024](bf16) @ Wt^T(bf16) + bias(f32).
// 128x128 tile, BK=32, 4 waves x (64x64 as 4x4 of 16x16x32 MFMAs).
// mode 0: out[gr*1024+gc]            (plain [B*T,E])
// mode 1: out[((b*H+h)*T+t)*D+d]     ([B,H,T,D] for Q,K)
// mode 2: out[((b*H+h)*D+d)*T+t]     ([B,H,D,T] for V)
#define LDA 40

template <typename OutT>
__device__ __forceinline__ void gemm_body(const __bf16* __restrict__ A,
                                          const __bf16* __restrict__ Bt,
                                          const float* __restrict__ bias,
                                          OutT* __restrict__ out,
                                          int mode, int bx, int by)
{
    alignas(16) __shared__ __bf16 As[128 * LDA];
    alignas(16) __shared__ __bf16 Bs[128 * LDA];

    int tid  = threadIdx.x;
    int lane = tid & 63;
    int wave = tid >> 6;
    int quad = lane >> 4;
    int l16  = lane & 15;
    int wm   = wave >> 1, wn = wave & 1;

    f4_t acc[4][4];
    #pragma unroll
    for (int i = 0; i < 4; i++)
        #pragma unroll
        for (int j = 0; j < 4; j++)
            acc[i][j] = f4_t{0.f, 0.f, 0.f, 0.f};

    for (int kt = 0; kt < 1024; kt += 32) {
        #pragma unroll
        for (int i = 0; i < 2; i++) {
            int c   = tid + 256 * i;      // 0..511
            int row = c >> 2;             // 0..127
            int kc  = (c & 3) * 8;        // 0,8,16,24
            *reinterpret_cast<bf8_t*>(&As[row * LDA + kc]) =
                *reinterpret_cast<const bf8_t*>(A + (size_t)(by * 128 + row) * 1024 + kt + kc);
            *reinterpret_cast<bf8_t*>(&Bs[row * LDA + kc]) =
                *reinterpret_cast<const bf8_t*>(Bt + (size_t)(bx * 128 + row) * 1024 + kt + kc);
        }
        __syncthreads();

        bf8_t af[4], bfr[4];
        #pragma unroll
        for (int im = 0; im < 4; im++)
            af[im] = *reinterpret_cast<const bf8_t*>(&As[(wm * 64 + im * 16 + l16) * LDA + quad * 8]);
        #pragma unroll
        for (int in_ = 0; in_ < 4; in_++)
            bfr[in_] = *reinterpret_cast<const bf8_t*>(&Bs[(wn * 64 + in_ * 16 + l16) * LDA + quad * 8]);
        #pragma unroll
        for (int im = 0; im < 4; im++)
            #pragma unroll
            for (int in_ = 0; in_ < 4; in_++)
                acc[im][in_] = __builtin_amdgcn_mfma_f32_16x16x32_bf16(
                    af[im], bfr[in_], acc[im][in_], 0, 0, 0);
        __syncthreads();
    }

    #pragma unroll
    for (int im = 0; im < 4; im++) {
        #pragma unroll
        for (int in_ = 0; in_ < 4; in_++) {
            int gc  = bx * 128 + wn * 64 + in_ * 16 + l16;
            float bb = bias[gc];
            int gr0 = by * 128 + wm * 64 + im * 16 + quad * 4;
            #pragma unroll
            for (int r = 0; r < 4; r++) {
                int gr  = gr0 + r;
                float v = acc[im][in_][r] + bb;
                size_t idx;
                if (mode == 0) {
                    idx = (size_t)gr * 1024 + gc;
                } else {
                    int b = gr >> 11, t = gr & 2047;
                    int h = gc >> 6,  d = gc & 63;
                    if (mode == 1) idx = ((size_t)(b * Hh + h) * Tt + t) * Dd + d;
                    else           idx = ((size_t)(b * Hh + h) * Dd + d) * Tt + t;
                }
                out[idx] = (OutT)v;
            }
        }
    }
}

__global__ __launch_bounds__(256) void gemm_qkv_kernel(
    const __bf16* __restrict__ A,
    const __bf16* __restrict__ WqT, const __bf16* __restrict__ WkT, const __bf16* __restrict__ WvT,
    const float* __restrict__ bq,  const float* __restrict__ bk,  const float* __restrict__ bv,
    __bf16* __restrict__ Qo, __bf16* __restrict__ Ko, __bf16* __restrict__ Vo)
{
    const __bf16* Bt; const float* bias; __bf16* out; int mode;
    if      (blockIdx.z == 0) { Bt = WqT; bias = bq; out = Qo; mode = 1; }
    else if (blockIdx.z == 1) { Bt = WkT; bias = bk; out = Ko; mode = 1; }
    else                      { Bt = WvT; bias = bv; out = Vo; mode = 2; }
    gemm_body<__bf16>(A, Bt, bias, out, mode, blockIdx.x, blockIdx.y);
}

__global__ __launch_bounds__(256) void gemm_out_kernel(
    const __bf16* __restrict__ A, const __bf16* __restrict__ Bt,
    const float* __restrict__ bias, float* __restrict__ out)
{
    gemm_body<float>(A, Bt, bias, out, 0, blockIdx.x, blockIdx.y);
}

// ---------------------------------------------------------------- flash attn
// grid (T/64, H, B), 256 threads. Wave w handles q rows q0+16w..+15.
// K tile [64 key][64 d] and V^T tile [64 d][64 key] in LDS (stride 72).
// S layout (C/D): row=quad*4+r, col=l16. P -> LDS -> A-layout for PV.
__global__ __launch_bounds__(256) void flash_kernel(
    const __bf16* __restrict__ Qb, const __bf16* __restrict__ Kb,
    const __bf16* __restrict__ Vb, const int* __restrict__ mask,
    __bf16* __restrict__ Zb)
{
    alignas(16) __shared__ __bf16 Ks[64 * 72];
    alignas(16) __shared__ __bf16 Vs[64 * 72];
    alignas(16) __shared__ __bf16 Ps[4 * 16 * 72];

    int tid  = threadIdx.x;
    int lane = tid & 63;
    int wave = tid >> 6;
    int quad = lane >> 4;
    int l16  = lane & 15;
    int b = blockIdx.z, h = blockIdx.y;
    int bh = b * Hh + h;
    int q0 = blockIdx.x * 64;
    int qrow = q0 + wave * 16;

    bf8_t qf[2];
    #pragma unroll
    for (int c = 0; c < 2; c++)
        qf[c] = *reinterpret_cast<const bf8_t*>(
            Qb + ((size_t)bh * Tt + qrow + l16) * Dd + c * 32 + quad * 8);

    float m_i[4], l_i[4];
    f4_t o[4];
    #pragma unroll
    for (int r = 0; r < 4; r++) { m_i[r] = -1e30f; l_i[r] = 0.f; }
    #pragma unroll
    for (int d = 0; d < 4; d++) o[d] = f4_t{0.f, 0.f, 0.f, 0.f};

    const float scale = 0.125f;   // D^-0.5
    const int pbase = wave * 16 * 72;

    for (int kt = 0; kt < Tt; kt += 64) {
        #pragma unroll
        for (int i = 0; i < 2; i++) {
            int c   = tid + 256 * i;   // 0..511
            int row = c >> 3;          // 0..63
            int dc  = (c & 7) * 8;
            *reinterpret_cast<bf8_t*>(&Ks[row * 72 + dc]) =
                *reinterpret_cast<const bf8_t*>(Kb + ((size_t)bh * Tt + kt + row) * Dd + dc);
            *reinterpret_cast<bf8_t*>(&Vs[row * 72 + dc]) =
                *reinterpret_cast<const bf8_t*>(Vb + ((size_t)bh * Dd + row) * Tt + kt + dc);
        }
        __syncthreads();

        // S = Q K^T : 4 key-subtiles of 16, K-depth 64 via 2 chunks
        f4_t s[4];
        #pragma unroll
        for (int n = 0; n < 4; n++) {
            s[n] = f4_t{0.f, 0.f, 0.f, 0.f};
            #pragma unroll
            for (int c = 0; c < 2; c++) {
                bf8_t kf = *reinterpret_cast<const bf8_t*>(
                    &Ks[(n * 16 + l16) * 72 + c * 32 + quad * 8]);
                s[n] = __builtin_amdgcn_mfma_f32_16x16x32_bf16(qf[c], kf, s[n], 0, 0, 0);
            }
        }

        // scale + mask + row max
        float sv[4][4];
        float mx[4] = {-1e30f, -1e30f, -1e30f, -1e30f};
        #pragma unroll
        for (int n = 0; n < 4; n++) {
            int kg = kt + n * 16 + l16;
            #pragma unroll
            for (int r = 0; r < 4; r++) {
                int qg = qrow + quad * 4 + r;
                int mv = mask[((size_t)b * Tt + qg) * Tt + kg];
                float v = (mv != 0) ? s[n][r] * scale : -1e30f;
                sv[n][r] = v;
                mx[r] = fmaxf(mx[r], v);
            }
        }
        #pragma unroll
        for (int off = 8; off >= 1; off >>= 1)
            #pragma unroll
            for (int r = 0; r < 4; r++)
                mx[r] = fmaxf(mx[r], __shfl_xor(mx[r], off, 16));

        float al[4], rs[4];
        #pragma unroll
        for (int r = 0; r < 4; r++) {
            float mnew = fmaxf(m_i[r], mx[r]);
            al[r] = __expf(m_i[r] - mnew);
            m_i[r] = mnew;
            rs[r] = 0.f;
        }
        // P = exp(S - m), store to LDS (bf16); accumulate row sums of the
        // *rounded* P so numerator/denominator match.
        #pragma unroll
        for (int n = 0; n < 4; n++) {
            #pragma unroll
            for (int r = 0; r < 4; r++) {
                float p = __expf(sv[n][r] - m_i[r]);
                __bf16 pb = (__bf16)p;
                rs[r] += (float)pb;
                Ps[pbase + (quad * 4 + r) * 72 + n * 16 + l16] = pb;
            }
        }
        #pragma unroll
        for (int off = 8; off >= 1; off >>= 1)
            #pragma unroll
            for (int r = 0; r < 4; r++)
                rs[r] += __shfl_xor(rs[r], off, 16);

        #pragma unroll
        for (int r = 0; r < 4; r++) l_i[r] = l_i[r] * al[r] + rs[r];
        #pragma unroll
        for (int ds = 0; ds < 4; ds++)
            #pragma unroll
            for (int r = 0; r < 4; r++)
                o[ds][r] *= al[r];

        // O += P @ V   (P: A-layout from LDS; V^T: B-layout, contiguous)
        #pragma unroll
        for (int c = 0; c < 2; c++) {
            bf8_t pf = *reinterpret_cast<const bf8_t*>(
                &Ps[pbase + l16 * 72 + c * 32 + quad * 8]);
            #pragma unroll
            for (int ds = 0; ds < 4; ds++) {
                bf8_t vf = *reinterpret_cast<const bf8_t*>(
                    &Vs[(ds * 16 + l16) * 72 + c * 32 + quad * 8]);
                o[ds] = __builtin_amdgcn_mfma_f32_16x16x32_bf16(pf, vf, o[ds], 0, 0, 0);
            }
        }
        __syncthreads();
    }

    #pragma unroll
    for (int r = 0; r < 4; r++) {
        float inv = 1.f / fmaxf(l_i[r], 1e-30f);
        int qg = qrow + quad * 4 + r;
        #pragma unroll
        for (int ds = 0; ds < 4; ds++)
            Zb[((size_t)b * Tt + qg) * 1024 + h * 64 + ds * 16 + l16] =
                (__bf16)(o[ds][r] * inv);
    }
}

// ---------------------------------------------------------------- launch
extern "C" void kernel_launch(void* const* d_in, const int* in_sizes, int n_in,
                              void* d_out, int out_size, void* d_ws, size_t ws_size,
                              hipStream_t stream)
{
    (void)in_sizes; (void)n_in; (void)out_size; (void)ws_size;

    const float* embed = (const float*)d_in[0];
    const int*   mask  = (const int*)d_in[1];
    const float* Wq = (const float*)d_in[2];
    const float* bq = (const float*)d_in[3];
    const float* Wk = (const float*)d_in[4];
    const float* bk = (const float*)d_in[5];
    const float* Wv = (const float*)d_in[6];
    const float* bv = (const float*)d_in[7];
    const float* Wz = (const float*)d_in[8];
    const float* bz = (const float*)d_in[9];
    float* out = (float*)d_out;

    char* ws = (char*)d_ws;
    const size_t MB = (size_t)1024 * 1024;
    __bf16* WqT = (__bf16*)(ws + 0 * MB);    // 2MB each
    __bf16* WkT = (__bf16*)(ws + 2 * MB);
    __bf16* WvT = (__bf16*)(ws + 4 * MB);
    __bf16* WzT = (__bf16*)(ws + 6 * MB);
    __bf16* Eb  = (__bf16*)(ws + 8 * MB);    // 8MB each
    __bf16* Qb  = (__bf16*)(ws + 16 * MB);
    __bf16* Kb  = (__bf16*)(ws + 24 * MB);
    __bf16* Vb  = (__bf16*)(ws + 32 * MB);
    __bf16* Zb  = (__bf16*)(ws + 40 * MB);   // total 48MB

    convert_kernel<<<dim3(4096), 256, 0, stream>>>(embed, Eb);
    transpose_kernel<<<dim3(32, 32, 4), 256, 0, stream>>>(Wq, Wk, Wv, Wz,
                                                          WqT, WkT, WvT, WzT);
    gemm_qkv_kernel<<<dim3(8, 32, 3), 256, 0, stream>>>(Eb, WqT, WkT, WvT,
                                                        bq, bk, bv, Qb, Kb, Vb);
    flash_kernel<<<dim3(32, Hh, Bb), 256, 0, stream>>>(Qb, Kb, Vb, mask, Zb);
    gemm_out_kernel<<<dim3(8, 32, 1), 256, 0, stream>>>(Zb, WzT, bz, out);
}